// Round 12
// baseline (89.890 us; speedup 1.0000x reference)
//
#include <hip/hip_runtime.h>
#include <hip/hip_fp16.h>

// GCN 2-layer forward.  Round-25: push the verified R11 lever to its limit --
// A's block size 512->1024 (hw max).  Same 79 hist blocks (per-nchunk fixed
// cost unchanged, unlike R10's failed CHUNK halving); per-thread serial chains
// halve again (8 edge iters, 5 init/writeout iters).  gemm half regrids
// transparently (bitwise-identical hm1).  Everything else = R11 (76.0us).
// Pipeline (5 dispatches):
//   1. count_gemm1 (1024 thr): per-chunk LDS histogram (rank = LDS atomic
//                   return, u16), TRANSPOSED counts[node][chunk]; + x @ W1.
//   2. prefix_scale: WAVE-per-node shfl scan over chunk row -> counts
//                   prefixes + deg + dinv, then scales row: g1h=half(hm1*dinv).
//                   Wave n zeros the pad row.
//   3. fill:        csr[d*256 + counts[d][r] + rank[e]] = src (no atomics).
//   4. agg1g2:      WAVE-per-node fp16 gather (fp32 accum) + ReLU, then
//                   in-block gemm2: G2 = (h @ W2) * dinv, stride 48.
//   5. agg2:        WAVE-per-node; G2 (1.9MB) is L2-resident everywhere.

#define FEAT 128
#define CHUNK_LOG 13
#define CHUNK (1 << CHUNK_LOG)
#define G2S 48
#define RSTRIDE_LOG 8          // padded CSR row stride = 256 (Poisson(64) max ~120)

__device__ __forceinline__ int load_idx(const void* p, long long i, int is64) {
  if (is64) return (int)((const long long*)p)[i];
  return ((const int*)p)[i];
}

// Per-wave edge-dtype detection: sample the first 64 8-byte words.
// int64 edges: all values < n < 2^32 -> ballot 0. All lanes must be active.
__device__ __forceinline__ int detect_is64(const void* edges) {
  long long v = ((const long long*)edges)[threadIdx.x & 63];
  return __ballot(v < 0 || v >= (1LL << 32)) == 0ULL;
}

// Fused: blocks [0, nchunk) build per-chunk LDS histograms + per-edge rank(u16);
//        blocks [nchunk, ...) do hm1 = x @ W1 (4 rows x 4 cols per thread).
__global__ void count_gemm1_kernel(const void* edges, long long E, int nchunk,
                                   unsigned short* __restrict__ counts, int ncp,
                                   unsigned short* __restrict__ rank,
                                   const float* __restrict__ x,
                                   const float* __restrict__ W1,
                                   float* __restrict__ hm1, int n) {
  if ((int)blockIdx.x < nchunk) {
    extern __shared__ unsigned int hist[];  // (n+1)/2 packed u16 pairs
    int is64 = detect_is64(edges);
    int q = blockIdx.x;
    int nw = (n + 1) >> 1;
    for (int i = threadIdx.x; i < nw; i += blockDim.x) hist[i] = 0;
    __syncthreads();
    long long base = (long long)q << CHUNK_LOG;
    long long rem = E - base;
    int m = (rem < (long long)CHUNK) ? (int)rem : CHUNK;
    for (int t = threadIdx.x; t < m; t += blockDim.x) {
      long long e = base + t;
      int dst = load_idx(edges, E + e, is64);
      int sh = (dst & 1) << 4;
      unsigned int old = atomicAdd(&hist[dst >> 1], 1u << sh);
      rank[e] = (unsigned short)((old >> sh) & 0xffffu);
    }
    __syncthreads();
    // transposed write-out: counts[node][q]
    for (int i = threadIdx.x; i < nw; i += blockDim.x) {
      unsigned int v = hist[i];
      int node0 = i << 1;
      counts[(long long)node0 * ncp + q] = (unsigned short)(v & 0xffffu);
      if (node0 + 1 < n)
        counts[(long long)(node0 + 1) * ncp + q] = (unsigned short)(v >> 16);
    }
  } else {
    int tid = ((int)blockIdx.x - nchunk) * (int)blockDim.x + (int)threadIdx.x;
    int n4 = (n + 3) >> 2;
    if (tid >= n4 * 32) return;
    int i4 = tid >> 5;
    int j = (tid & 31) << 2;
    int r0 = i4 << 2;
    const float* xr = x + (long long)r0 * FEAT;
    if (r0 + 4 <= n) {
      float4 a0 = {0.f,0.f,0.f,0.f}, a1 = a0, a2 = a0, a3 = a0;
      #pragma unroll 4
      for (int k = 0; k < FEAT; ++k) {
        float4 w = *(const float4*)(W1 + k * FEAT + j);
        float x0 = xr[k];
        float x1 = xr[FEAT + k];
        float x2 = xr[2 * FEAT + k];
        float x3 = xr[3 * FEAT + k];
        a0.x = fmaf(x0, w.x, a0.x); a0.y = fmaf(x0, w.y, a0.y);
        a0.z = fmaf(x0, w.z, a0.z); a0.w = fmaf(x0, w.w, a0.w);
        a1.x = fmaf(x1, w.x, a1.x); a1.y = fmaf(x1, w.y, a1.y);
        a1.z = fmaf(x1, w.z, a1.z); a1.w = fmaf(x1, w.w, a1.w);
        a2.x = fmaf(x2, w.x, a2.x); a2.y = fmaf(x2, w.y, a2.y);
        a2.z = fmaf(x2, w.z, a2.z); a2.w = fmaf(x2, w.w, a2.w);
        a3.x = fmaf(x3, w.x, a3.x); a3.y = fmaf(x3, w.y, a3.y);
        a3.z = fmaf(x3, w.z, a3.z); a3.w = fmaf(x3, w.w, a3.w);
      }
      *(float4*)(hm1 + (long long)(r0 + 0) * FEAT + j) = a0;
      *(float4*)(hm1 + (long long)(r0 + 1) * FEAT + j) = a1;
      *(float4*)(hm1 + (long long)(r0 + 2) * FEAT + j) = a2;
      *(float4*)(hm1 + (long long)(r0 + 3) * FEAT + j) = a3;
    } else {
      for (int r = 0; r0 + r < n; ++r) {
        float4 a = {0.f,0.f,0.f,0.f};
        for (int k = 0; k < FEAT; ++k) {
          float4 w = *(const float4*)(W1 + k * FEAT + j);
          float xv = xr[(long long)r * FEAT + k];
          a.x = fmaf(xv, w.x, a.x); a.y = fmaf(xv, w.y, a.y);
          a.z = fmaf(xv, w.z, a.z); a.w = fmaf(xv, w.w, a.w);
        }
        *(float4*)(hm1 + (long long)(r0 + r) * FEAT + j) = a;
      }
    }
  }
}

// WAVE-per-node: chunk prefix -> counts prefixes + deg + dinv, then the SAME
// wave scales its row (g1h = half(hm1*dinv), 64 lanes x float2->half2).
// Wave i==n zeros the pad row.
__global__ void prefix_scale_kernel(unsigned short* counts, int ncp, int* deg,
                                    float* dinv,
                                    const float* __restrict__ hm1,
                                    __half* __restrict__ g1h, int n, int nchunk) {
  int i = (int)((blockIdx.x * (long long)blockDim.x + threadIdx.x) >> 6);
  int lane = threadIdx.x & 63;
  if (i > n) return;
  if (i == n) {  // zero pad row n (64 lanes x 4B = 256B)
    ((unsigned int*)(g1h + ((long long)n << 7)))[lane] = 0u;
    return;
  }
  int nw32 = (nchunk + 1) >> 1;
  int tot;
  if (nw32 <= 64) {
    unsigned int* r32 = (unsigned int*)(counts + (long long)i * ncp);
    unsigned int v = (lane < nw32) ? r32[lane] : 0u;
    int q0 = lane << 1;
    int c0 = (q0 < nchunk) ? (int)(v & 0xffffu) : 0;
    int c1 = (q0 + 1 < nchunk) ? (int)(v >> 16) : 0;
    int s = c0 + c1;
    int run = s;
    #pragma unroll
    for (int off = 1; off < 64; off <<= 1) {
      int t = __shfl_up(run, off);
      if (lane >= off) run += t;
    }
    int excl = run - s;
    if (lane < nw32)
      r32[lane] = (unsigned int)(excl & 0xffff) |
                  ((unsigned int)((excl + c0) & 0xffff) << 16);
    tot = __shfl(run, 63);
  } else {
    int run = 0;
    if (lane == 0) {
      for (int q = 0; q < nchunk; ++q) {
        long long idx = (long long)i * ncp + q;
        int c = counts[idx];
        counts[idx] = (unsigned short)run;
        run += c;
      }
    }
    tot = __shfl(run, 0);
  }
  float di = rsqrtf((float)tot + 1.0f);  // +1 = self loop
  if (lane == 0) { deg[i] = tot; dinv[i] = di; }
  // scale row i: hm1 (fp32) -> g1h (fp16), element-wise *di
  float2 v = ((const float2*)(hm1 + ((long long)i << 7)))[lane];
  __half2 hv = __floats2half2_rn(v.x * di, v.y * di);
  ((__half2*)g1h)[((long long)i << 6) + lane] = hv;
}

// Padded-CSR fill: pos = (d<<8) + counts[d][r] + rank[e] (u16, no atomics).
__global__ void fill_kernel(const void* edges, long long E,
                            const unsigned short* __restrict__ counts, int ncp,
                            const unsigned short* __restrict__ rank,
                            unsigned short* __restrict__ csr) {
  int is64 = detect_is64(edges);  // all lanes active here
  long long e = blockIdx.x * (long long)blockDim.x + threadIdx.x;
  if (e >= E) return;
  int r = (int)(e >> CHUNK_LOG);
  int s = load_idx(edges, e, is64);
  int d = load_idx(edges, E + e, is64);
  int pos = (d << RSTRIDE_LOG) + (int)counts[(long long)d * ncp + r] + (int)rank[e];
  csr[pos] = (unsigned short)s;
}

// Fused agg1 + gemm2.  4 waves = 4 nodes per block.
// Phase 1 (per wave): full-row gather, 64 lanes x __half2 (features 2*lane,
//   2*lane+1), fp32 accumulate; h = relu(di*(sum+self) + b1) -> LDS.
// Phase 2 (after one barrier): lanes 0..C-1 compute G2[node][c] =
//   di * sum_k h[k]*W2[k][c]  (k ascending).
__global__ void agg1g2_kernel(const __half* __restrict__ g,
                              const float* __restrict__ dinv,
                              const int* __restrict__ deg,
                              const unsigned short* __restrict__ csr,
                              const float* __restrict__ b1,
                              const float* __restrict__ W2,
                              float* __restrict__ G2, int n, int C) {
  __shared__ float hs[4][FEAT];  // 2 KB
  int lane = threadIdx.x & 63;
  int wid = threadIdx.x >> 6;
  int node = ((int)blockIdx.x << 2) | wid;
  if (node < n) {
    const unsigned int* gu = (const unsigned int*)g;  // 64 u32 per row
    int beg = node << RSTRIDE_LOG;
    int end = beg + deg[node];
    float ax = 0.f, ay = 0.f;
    for (int base = beg; base < end; base += 64) {
      int ed = (base + lane < end) ? (int)csr[base + lane] : n;  // n -> zero row
      int m = end - base; if (m > 64) m = 64;
      int mm = (m + 15) & ~15;
      for (int j = 0; j < mm; j += 16) {
        int ss[16];
        unsigned int vv[16];
        #pragma unroll
        for (int p = 0; p < 16; ++p) ss[p] = __shfl(ed, j + p);
        #pragma unroll
        for (int p = 0; p < 16; ++p) vv[p] = gu[(ss[p] << 6) + lane];
        #pragma unroll
        for (int p = 0; p < 16; ++p) {
          float2 v = __half22float2(*(__half2*)&vv[p]);
          ax += v.x; ay += v.y;
        }
      }
    }
    float di = dinv[node];
    float2 self = __half22float2(((const __half2*)g)[(node << 6) + lane]);
    ax += self.x; ay += self.y;
    int f = lane << 1;
    ax = fmaxf(ax * di + b1[f], 0.f);
    ay = fmaxf(ay * di + b1[f + 1], 0.f);
    float2* hp = (float2*)&hs[wid][f];
    *hp = make_float2(ax, ay);
  }
  __syncthreads();
  if (node < n) {
    if (lane < C) {
      const float* hr = hs[wid];
      float acc = 0.f;
      #pragma unroll 8
      for (int k = 0; k < FEAT; ++k)
        acc = fmaf(hr[k], W2[k * C + lane], acc);
      G2[node * G2S + lane] = acc * dinv[node];
    }
  } else if (node == n && lane < C) {
    G2[n * G2S + lane] = 0.f;  // pad row read by agg2
  }
}

// WAVE-per-node. out = di*(sum G2[src] + G2[node]) + b2. Lanes 0..C-1 active.
__global__ void agg2_kernel(const float* __restrict__ G2, const float* __restrict__ dinv,
                            const int* __restrict__ deg,
                            const unsigned short* __restrict__ csr,
                            const float* __restrict__ b2, float* __restrict__ out,
                            int n, int C) {
  int node = (int)((blockIdx.x * (long long)blockDim.x + threadIdx.x) >> 6);
  int lane = threadIdx.x & 63;
  if (node >= n) return;
  int beg = node << RSTRIDE_LOG;
  int end = beg + deg[node];
  float acc = 0.f;
  for (int base = beg; base < end; base += 64) {
    int ed = (base + lane < end) ? (int)csr[base + lane] : n;  // n -> zero row
    int m = end - base; if (m > 64) m = 64;
    int mm = (m + 15) & ~15;
    for (int j = 0; j < mm; j += 16) {
      int ss[16];
      float vv[16];
      #pragma unroll
      for (int p = 0; p < 16; ++p) ss[p] = __shfl(ed, j + p);
      #pragma unroll
      for (int p = 0; p < 16; ++p)
        vv[p] = (lane < C) ? G2[(long long)ss[p] * G2S + lane] : 0.f;
      #pragma unroll
      for (int p = 0; p < 16; ++p) acc += vv[p];
    }
  }
  if (lane < C) {
    float di = dinv[node];
    acc += G2[(long long)node * G2S + lane];
    out[(long long)node * C + lane] = acc * di + b2[lane];
  }
}

extern "C" void kernel_launch(void* const* d_in, const int* in_sizes, int n_in,
                              void* d_out, int out_size, void* d_ws, size_t ws_size,
                              hipStream_t stream) {
  const float* x     = (const float*)d_in[0];
  const void*  edges = d_in[1];
  const float* W1    = (const float*)d_in[2];
  const float* b1    = (const float*)d_in[3];
  const float* W2    = (const float*)d_in[4];
  const float* b2    = (const float*)d_in[5];
  float* out = (float*)d_out;

  const int n = in_sizes[0] / FEAT;
  const long long E = in_sizes[1] / 2;
  const int C = in_sizes[5];
  const int nchunk = (int)((E + CHUNK - 1) >> CHUNK_LOG);
  const int ncp = (nchunk + 1) & ~1;   // even stride (u32-packable rows)

  char* ws = (char*)d_ws;
  size_t off = 0;
  auto alloc = [&](size_t bytes) -> void* {
    void* p = ws + off;
    off = (off + bytes + 255) & ~(size_t)255;
    return p;
  };
  unsigned short* counts = (unsigned short*)alloc(2ll * ncp * n);  // [node][chunk]
  unsigned short* rank   = (unsigned short*)alloc(2ll * E);
  unsigned short* csr    = (unsigned short*)alloc(2ll * n << RSTRIDE_LOG);  // padded
  int*   deg     = (int*)alloc(4ll * n);
  float* dinv    = (float*)alloc(4ll * n);
  float* hm1     = (float*)alloc(4ll * n * FEAT);        // fp32 x @ W1
  __half* g1h    = (__half*)alloc(2ll * (n + 1) * FEAT); // half(hm1*dinv); row n zero
  float* G2      = (float*)alloc(4ll * (n + 1) * G2S);   // row n zero

  int n4 = (n + 3) >> 2;
  const int ABLK = 1024;                           // A block size (hw max)
  int gemmBlocks = (n4 * 32 + ABLK - 1) / ABLK;
  int blocksE = (int)((E + 255) / 256);
  size_t ldsBytes = (size_t)((n + 1) >> 1) * 4;  // 20 KB at n=10000

  count_gemm1_kernel<<<nchunk + gemmBlocks, ABLK, ldsBytes, stream>>>(
      edges, E, nchunk, counts, ncp, rank, x, W1, hm1, n);
  prefix_scale_kernel<<<(int)(((long long)(n + 1) * 64 + 255) / 256), 256, 0,
                        stream>>>(counts, ncp, deg, dinv, hm1, g1h, n, nchunk);
  fill_kernel<<<blocksE, 256, 0, stream>>>(edges, E, counts, ncp, rank, csr);
  int aggBlocks = (n + 4) >> 2;   // covers nodes 0..n (pad row in last block)
  agg1g2_kernel<<<aggBlocks, 256, 0, stream>>>(g1h, dinv, deg, csr, b1, W2,
                                               G2, n, C);
  agg2_kernel<<<(n4 * 256 + 255) / 256, 256, 0, stream>>>(G2, dinv, deg, csr,
                                                          b2, out, n, C);
}

// Round 13
// 76.145 us; speedup vs baseline: 1.1805x; 1.1805x over previous
//
#include <hip/hip_runtime.h>
#include <hip/hip_fp16.h>

// GCN 2-layer forward.  Round-26: revert R12's ABLK 1024 (157 total blocks
// < 256 CUs -> chip underfill, +14us; 512 is the verified sweet spot).
// R11 base (76.0us) + 4-wide vectorized hist edge processing: one int4 (or
// 2x longlong2) coalesced load = 4 dsts, 4 LDS atomics, one ushort4 rank
// store -- per-thread load/store instruction chains drop 16->4 while the 79
// hist blocks' low TLP (2 waves/SIMD) stays latency-hidden by pipelined
// loads.  Tail chunk + unaligned-E fall back to the scalar path.
// Pipeline (5 dispatches):
//   1. count_gemm1 (512 thr): per-chunk LDS histogram (rank = LDS atomic
//                   return, u16), TRANSPOSED counts[node][chunk]; + x @ W1.
//   2. prefix_scale: WAVE-per-node shfl scan over chunk row -> counts
//                   prefixes + deg + dinv, then scales row: g1h=half(hm1*dinv).
//                   Wave n zeros the pad row.
//   3. fill:        csr[d*256 + counts[d][r] + rank[e]] = src (no atomics).
//   4. agg1g2:      WAVE-per-node fp16 gather (fp32 accum) + ReLU, then
//                   in-block gemm2: G2 = (h @ W2) * dinv, stride 48.
//   5. agg2:        WAVE-per-node; G2 (1.9MB) is L2-resident everywhere.

#define FEAT 128
#define CHUNK_LOG 13
#define CHUNK (1 << CHUNK_LOG)
#define G2S 48
#define RSTRIDE_LOG 8          // padded CSR row stride = 256 (Poisson(64) max ~120)

__device__ __forceinline__ int load_idx(const void* p, long long i, int is64) {
  if (is64) return (int)((const long long*)p)[i];
  return ((const int*)p)[i];
}

// Per-wave edge-dtype detection: sample the first 64 8-byte words.
// int64 edges: all values < n < 2^32 -> ballot 0. All lanes must be active.
__device__ __forceinline__ int detect_is64(const void* edges) {
  long long v = ((const long long*)edges)[threadIdx.x & 63];
  return __ballot(v < 0 || v >= (1LL << 32)) == 0ULL;
}

// Fused: blocks [0, nchunk) build per-chunk LDS histograms + per-edge rank(u16);
//        blocks [nchunk, ...) do hm1 = x @ W1 (4 rows x 4 cols per thread).
__global__ void count_gemm1_kernel(const void* edges, long long E, int nchunk,
                                   unsigned short* __restrict__ counts, int ncp,
                                   unsigned short* __restrict__ rank,
                                   const float* __restrict__ x,
                                   const float* __restrict__ W1,
                                   float* __restrict__ hm1, int n) {
  if ((int)blockIdx.x < nchunk) {
    extern __shared__ unsigned int hist[];  // (n+1)/2 packed u16 pairs
    int is64 = detect_is64(edges);
    int q = blockIdx.x;
    int nw = (n + 1) >> 1;
    for (int i = threadIdx.x; i < nw; i += blockDim.x) hist[i] = 0;
    __syncthreads();
    long long base = (long long)q << CHUNK_LOG;
    long long rem = E - base;
    int m = (rem < (long long)CHUNK) ? (int)rem : CHUNK;
    // 4-wide vector path: full chunk + aligned dst-array start.
    bool vec_ok = (m == CHUNK) && (is64 ? ((E & 1) == 0) : ((E & 3) == 0));
    if (vec_ok) {
      for (int gidx = threadIdx.x; gidx < (CHUNK >> 2); gidx += blockDim.x) {
        long long e0 = base + ((long long)gidx << 2);
        int d0, d1, d2, d3;
        if (is64) {
          const longlong2* p2 = (const longlong2*)edges;
          longlong2 a = p2[(E + e0) >> 1];
          longlong2 b = p2[((E + e0) >> 1) + 1];
          d0 = (int)a.x; d1 = (int)a.y; d2 = (int)b.x; d3 = (int)b.y;
        } else {
          int4 a = ((const int4*)edges)[(E + e0) >> 2];
          d0 = a.x; d1 = a.y; d2 = a.z; d3 = a.w;
        }
        ushort4 rk;
        {
          int sh = (d0 & 1) << 4;
          unsigned int old = atomicAdd(&hist[d0 >> 1], 1u << sh);
          rk.x = (unsigned short)((old >> sh) & 0xffffu);
        }
        {
          int sh = (d1 & 1) << 4;
          unsigned int old = atomicAdd(&hist[d1 >> 1], 1u << sh);
          rk.y = (unsigned short)((old >> sh) & 0xffffu);
        }
        {
          int sh = (d2 & 1) << 4;
          unsigned int old = atomicAdd(&hist[d2 >> 1], 1u << sh);
          rk.z = (unsigned short)((old >> sh) & 0xffffu);
        }
        {
          int sh = (d3 & 1) << 4;
          unsigned int old = atomicAdd(&hist[d3 >> 1], 1u << sh);
          rk.w = (unsigned short)((old >> sh) & 0xffffu);
        }
        *(ushort4*)(rank + e0) = rk;
      }
    } else {
      for (int t = threadIdx.x; t < m; t += blockDim.x) {
        long long e = base + t;
        int dst = load_idx(edges, E + e, is64);
        int sh = (dst & 1) << 4;
        unsigned int old = atomicAdd(&hist[dst >> 1], 1u << sh);
        rank[e] = (unsigned short)((old >> sh) & 0xffffu);
      }
    }
    __syncthreads();
    // transposed write-out: counts[node][q]
    for (int i = threadIdx.x; i < nw; i += blockDim.x) {
      unsigned int v = hist[i];
      int node0 = i << 1;
      counts[(long long)node0 * ncp + q] = (unsigned short)(v & 0xffffu);
      if (node0 + 1 < n)
        counts[(long long)(node0 + 1) * ncp + q] = (unsigned short)(v >> 16);
    }
  } else {
    int tid = ((int)blockIdx.x - nchunk) * (int)blockDim.x + (int)threadIdx.x;
    int n4 = (n + 3) >> 2;
    if (tid >= n4 * 32) return;
    int i4 = tid >> 5;
    int j = (tid & 31) << 2;
    int r0 = i4 << 2;
    const float* xr = x + (long long)r0 * FEAT;
    if (r0 + 4 <= n) {
      float4 a0 = {0.f,0.f,0.f,0.f}, a1 = a0, a2 = a0, a3 = a0;
      #pragma unroll 4
      for (int k = 0; k < FEAT; ++k) {
        float4 w = *(const float4*)(W1 + k * FEAT + j);
        float x0 = xr[k];
        float x1 = xr[FEAT + k];
        float x2 = xr[2 * FEAT + k];
        float x3 = xr[3 * FEAT + k];
        a0.x = fmaf(x0, w.x, a0.x); a0.y = fmaf(x0, w.y, a0.y);
        a0.z = fmaf(x0, w.z, a0.z); a0.w = fmaf(x0, w.w, a0.w);
        a1.x = fmaf(x1, w.x, a1.x); a1.y = fmaf(x1, w.y, a1.y);
        a1.z = fmaf(x1, w.z, a1.z); a1.w = fmaf(x1, w.w, a1.w);
        a2.x = fmaf(x2, w.x, a2.x); a2.y = fmaf(x2, w.y, a2.y);
        a2.z = fmaf(x2, w.z, a2.z); a2.w = fmaf(x2, w.w, a2.w);
        a3.x = fmaf(x3, w.x, a3.x); a3.y = fmaf(x3, w.y, a3.y);
        a3.z = fmaf(x3, w.z, a3.z); a3.w = fmaf(x3, w.w, a3.w);
      }
      *(float4*)(hm1 + (long long)(r0 + 0) * FEAT + j) = a0;
      *(float4*)(hm1 + (long long)(r0 + 1) * FEAT + j) = a1;
      *(float4*)(hm1 + (long long)(r0 + 2) * FEAT + j) = a2;
      *(float4*)(hm1 + (long long)(r0 + 3) * FEAT + j) = a3;
    } else {
      for (int r = 0; r0 + r < n; ++r) {
        float4 a = {0.f,0.f,0.f,0.f};
        for (int k = 0; k < FEAT; ++k) {
          float4 w = *(const float4*)(W1 + k * FEAT + j);
          float xv = xr[(long long)r * FEAT + k];
          a.x = fmaf(xv, w.x, a.x); a.y = fmaf(xv, w.y, a.y);
          a.z = fmaf(xv, w.z, a.z); a.w = fmaf(xv, w.w, a.w);
        }
        *(float4*)(hm1 + (long long)(r0 + r) * FEAT + j) = a;
      }
    }
  }
}

// WAVE-per-node: chunk prefix -> counts prefixes + deg + dinv, then the SAME
// wave scales its row (g1h = half(hm1*dinv), 64 lanes x float2->half2).
// Wave i==n zeros the pad row.
__global__ void prefix_scale_kernel(unsigned short* counts, int ncp, int* deg,
                                    float* dinv,
                                    const float* __restrict__ hm1,
                                    __half* __restrict__ g1h, int n, int nchunk) {
  int i = (int)((blockIdx.x * (long long)blockDim.x + threadIdx.x) >> 6);
  int lane = threadIdx.x & 63;
  if (i > n) return;
  if (i == n) {  // zero pad row n (64 lanes x 4B = 256B)
    ((unsigned int*)(g1h + ((long long)n << 7)))[lane] = 0u;
    return;
  }
  int nw32 = (nchunk + 1) >> 1;
  int tot;
  if (nw32 <= 64) {
    unsigned int* r32 = (unsigned int*)(counts + (long long)i * ncp);
    unsigned int v = (lane < nw32) ? r32[lane] : 0u;
    int q0 = lane << 1;
    int c0 = (q0 < nchunk) ? (int)(v & 0xffffu) : 0;
    int c1 = (q0 + 1 < nchunk) ? (int)(v >> 16) : 0;
    int s = c0 + c1;
    int run = s;
    #pragma unroll
    for (int off = 1; off < 64; off <<= 1) {
      int t = __shfl_up(run, off);
      if (lane >= off) run += t;
    }
    int excl = run - s;
    if (lane < nw32)
      r32[lane] = (unsigned int)(excl & 0xffff) |
                  ((unsigned int)((excl + c0) & 0xffff) << 16);
    tot = __shfl(run, 63);
  } else {
    int run = 0;
    if (lane == 0) {
      for (int q = 0; q < nchunk; ++q) {
        long long idx = (long long)i * ncp + q;
        int c = counts[idx];
        counts[idx] = (unsigned short)run;
        run += c;
      }
    }
    tot = __shfl(run, 0);
  }
  float di = rsqrtf((float)tot + 1.0f);  // +1 = self loop
  if (lane == 0) { deg[i] = tot; dinv[i] = di; }
  // scale row i: hm1 (fp32) -> g1h (fp16), element-wise *di
  float2 v = ((const float2*)(hm1 + ((long long)i << 7)))[lane];
  __half2 hv = __floats2half2_rn(v.x * di, v.y * di);
  ((__half2*)g1h)[((long long)i << 6) + lane] = hv;
}

// Padded-CSR fill: pos = (d<<8) + counts[d][r] + rank[e] (u16, no atomics).
__global__ void fill_kernel(const void* edges, long long E,
                            const unsigned short* __restrict__ counts, int ncp,
                            const unsigned short* __restrict__ rank,
                            unsigned short* __restrict__ csr) {
  int is64 = detect_is64(edges);  // all lanes active here
  long long e = blockIdx.x * (long long)blockDim.x + threadIdx.x;
  if (e >= E) return;
  int r = (int)(e >> CHUNK_LOG);
  int s = load_idx(edges, e, is64);
  int d = load_idx(edges, E + e, is64);
  int pos = (d << RSTRIDE_LOG) + (int)counts[(long long)d * ncp + r] + (int)rank[e];
  csr[pos] = (unsigned short)s;
}

// Fused agg1 + gemm2.  4 waves = 4 nodes per block.
// Phase 1 (per wave): full-row gather, 64 lanes x __half2 (features 2*lane,
//   2*lane+1), fp32 accumulate; h = relu(di*(sum+self) + b1) -> LDS.
// Phase 2 (after one barrier): lanes 0..C-1 compute G2[node][c] =
//   di * sum_k h[k]*W2[k][c]  (k ascending).
__global__ void agg1g2_kernel(const __half* __restrict__ g,
                              const float* __restrict__ dinv,
                              const int* __restrict__ deg,
                              const unsigned short* __restrict__ csr,
                              const float* __restrict__ b1,
                              const float* __restrict__ W2,
                              float* __restrict__ G2, int n, int C) {
  __shared__ float hs[4][FEAT];  // 2 KB
  int lane = threadIdx.x & 63;
  int wid = threadIdx.x >> 6;
  int node = ((int)blockIdx.x << 2) | wid;
  if (node < n) {
    const unsigned int* gu = (const unsigned int*)g;  // 64 u32 per row
    int beg = node << RSTRIDE_LOG;
    int end = beg + deg[node];
    float ax = 0.f, ay = 0.f;
    for (int base = beg; base < end; base += 64) {
      int ed = (base + lane < end) ? (int)csr[base + lane] : n;  // n -> zero row
      int m = end - base; if (m > 64) m = 64;
      int mm = (m + 15) & ~15;
      for (int j = 0; j < mm; j += 16) {
        int ss[16];
        unsigned int vv[16];
        #pragma unroll
        for (int p = 0; p < 16; ++p) ss[p] = __shfl(ed, j + p);
        #pragma unroll
        for (int p = 0; p < 16; ++p) vv[p] = gu[(ss[p] << 6) + lane];
        #pragma unroll
        for (int p = 0; p < 16; ++p) {
          float2 v = __half22float2(*(__half2*)&vv[p]);
          ax += v.x; ay += v.y;
        }
      }
    }
    float di = dinv[node];
    float2 self = __half22float2(((const __half2*)g)[(node << 6) + lane]);
    ax += self.x; ay += self.y;
    int f = lane << 1;
    ax = fmaxf(ax * di + b1[f], 0.f);
    ay = fmaxf(ay * di + b1[f + 1], 0.f);
    float2* hp = (float2*)&hs[wid][f];
    *hp = make_float2(ax, ay);
  }
  __syncthreads();
  if (node < n) {
    if (lane < C) {
      const float* hr = hs[wid];
      float acc = 0.f;
      #pragma unroll 8
      for (int k = 0; k < FEAT; ++k)
        acc = fmaf(hr[k], W2[k * C + lane], acc);
      G2[node * G2S + lane] = acc * dinv[node];
    }
  } else if (node == n && lane < C) {
    G2[n * G2S + lane] = 0.f;  // pad row read by agg2
  }
}

// WAVE-per-node. out = di*(sum G2[src] + G2[node]) + b2. Lanes 0..C-1 active.
__global__ void agg2_kernel(const float* __restrict__ G2, const float* __restrict__ dinv,
                            const int* __restrict__ deg,
                            const unsigned short* __restrict__ csr,
                            const float* __restrict__ b2, float* __restrict__ out,
                            int n, int C) {
  int node = (int)((blockIdx.x * (long long)blockDim.x + threadIdx.x) >> 6);
  int lane = threadIdx.x & 63;
  if (node >= n) return;
  int beg = node << RSTRIDE_LOG;
  int end = beg + deg[node];
  float acc = 0.f;
  for (int base = beg; base < end; base += 64) {
    int ed = (base + lane < end) ? (int)csr[base + lane] : n;  // n -> zero row
    int m = end - base; if (m > 64) m = 64;
    int mm = (m + 15) & ~15;
    for (int j = 0; j < mm; j += 16) {
      int ss[16];
      float vv[16];
      #pragma unroll
      for (int p = 0; p < 16; ++p) ss[p] = __shfl(ed, j + p);
      #pragma unroll
      for (int p = 0; p < 16; ++p)
        vv[p] = (lane < C) ? G2[(long long)ss[p] * G2S + lane] : 0.f;
      #pragma unroll
      for (int p = 0; p < 16; ++p) acc += vv[p];
    }
  }
  if (lane < C) {
    float di = dinv[node];
    acc += G2[(long long)node * G2S + lane];
    out[(long long)node * C + lane] = acc * di + b2[lane];
  }
}

extern "C" void kernel_launch(void* const* d_in, const int* in_sizes, int n_in,
                              void* d_out, int out_size, void* d_ws, size_t ws_size,
                              hipStream_t stream) {
  const float* x     = (const float*)d_in[0];
  const void*  edges = d_in[1];
  const float* W1    = (const float*)d_in[2];
  const float* b1    = (const float*)d_in[3];
  const float* W2    = (const float*)d_in[4];
  const float* b2    = (const float*)d_in[5];
  float* out = (float*)d_out;

  const int n = in_sizes[0] / FEAT;
  const long long E = in_sizes[1] / 2;
  const int C = in_sizes[5];
  const int nchunk = (int)((E + CHUNK - 1) >> CHUNK_LOG);
  const int ncp = (nchunk + 1) & ~1;   // even stride (u32-packable rows)

  char* ws = (char*)d_ws;
  size_t off = 0;
  auto alloc = [&](size_t bytes) -> void* {
    void* p = ws + off;
    off = (off + bytes + 255) & ~(size_t)255;
    return p;
  };
  unsigned short* counts = (unsigned short*)alloc(2ll * ncp * n);  // [node][chunk]
  unsigned short* rank   = (unsigned short*)alloc(2ll * E);
  unsigned short* csr    = (unsigned short*)alloc(2ll * n << RSTRIDE_LOG);  // padded
  int*   deg     = (int*)alloc(4ll * n);
  float* dinv    = (float*)alloc(4ll * n);
  float* hm1     = (float*)alloc(4ll * n * FEAT);        // fp32 x @ W1
  __half* g1h    = (__half*)alloc(2ll * (n + 1) * FEAT); // half(hm1*dinv); row n zero
  float* G2      = (float*)alloc(4ll * (n + 1) * G2S);   // row n zero

  int n4 = (n + 3) >> 2;
  const int ABLK = 512;                            // A block size (R11 verified)
  int gemmBlocks = (n4 * 32 + ABLK - 1) / ABLK;
  int blocksE = (int)((E + 255) / 256);
  size_t ldsBytes = (size_t)((n + 1) >> 1) * 4;  // 20 KB at n=10000

  count_gemm1_kernel<<<nchunk + gemmBlocks, ABLK, ldsBytes, stream>>>(
      edges, E, nchunk, counts, ncp, rank, x, W1, hm1, n);
  prefix_scale_kernel<<<(int)(((long long)(n + 1) * 64 + 255) / 256), 256, 0,
                        stream>>>(counts, ncp, deg, dinv, hm1, g1h, n, nchunk);
  fill_kernel<<<blocksE, 256, 0, stream>>>(edges, E, counts, ncp, rank, csr);
  int aggBlocks = (n + 4) >> 2;   // covers nodes 0..n (pad row in last block)
  agg1g2_kernel<<<aggBlocks, 256, 0, stream>>>(g1h, dinv, deg, csr, b1, W2,
                                               G2, n, C);
  agg2_kernel<<<(n4 * 256 + 255) / 256, 256, 0, stream>>>(G2, dinv, deg, csr,
                                                          b2, out, n, C);
}

// Round 14
// 75.651 us; speedup vs baseline: 1.1882x; 1.0065x over previous
//
#include <hip/hip_runtime.h>
#include <hip/hip_fp16.h>

// GCN 2-layer forward.  Round-27: two bitwise-identical issue/latency cuts on
// the R13 base (76.1us):
//   (a) A's gemm half loads x as float4 (20 -> 8 load instrs per 64 fma;
//       k-order per output unchanged -> hm1 bit-identical).
//   (b) agg1g2 stages W2 (20KB) into LDS once per block; phase-2's 128
//       loads/node hit LDS (~30cy, <=2-way bank alias) instead of L2
//       (~200cy).  Same values, same k order -> bit-identical.
// Pipeline (5 dispatches):
//   1. count_gemm1 (512 thr): per-chunk LDS histogram (rank = LDS atomic
//                   return, u16), TRANSPOSED counts[node][chunk]; + x @ W1.
//   2. prefix_scale: WAVE-per-node shfl scan over chunk row -> counts
//                   prefixes + deg + dinv, then scales row: g1h=half(hm1*dinv).
//                   Wave n zeros the pad row.
//   3. fill:        csr[d*256 + counts[d][r] + rank[e]] = src (no atomics).
//   4. agg1g2:      WAVE-per-node fp16 gather (fp32 accum) + ReLU, then
//                   in-block gemm2 vs LDS-staged W2: G2 = (h @ W2) * dinv.
//   5. agg2:        WAVE-per-node; G2 (1.9MB) is L2-resident everywhere.

#define FEAT 128
#define CHUNK_LOG 13
#define CHUNK (1 << CHUNK_LOG)
#define G2S 48
#define RSTRIDE_LOG 8          // padded CSR row stride = 256 (Poisson(64) max ~120)

__device__ __forceinline__ int load_idx(const void* p, long long i, int is64) {
  if (is64) return (int)((const long long*)p)[i];
  return ((const int*)p)[i];
}

// Per-wave edge-dtype detection: sample the first 64 8-byte words.
// int64 edges: all values < n < 2^32 -> ballot 0. All lanes must be active.
__device__ __forceinline__ int detect_is64(const void* edges) {
  long long v = ((const long long*)edges)[threadIdx.x & 63];
  return __ballot(v < 0 || v >= (1LL << 32)) == 0ULL;
}

// Fused: blocks [0, nchunk) build per-chunk LDS histograms + per-edge rank(u16);
//        blocks [nchunk, ...) do hm1 = x @ W1 (4 rows x 4 cols per thread).
__global__ void count_gemm1_kernel(const void* edges, long long E, int nchunk,
                                   unsigned short* __restrict__ counts, int ncp,
                                   unsigned short* __restrict__ rank,
                                   const float* __restrict__ x,
                                   const float* __restrict__ W1,
                                   float* __restrict__ hm1, int n) {
  if ((int)blockIdx.x < nchunk) {
    extern __shared__ unsigned int hist[];  // (n+1)/2 packed u16 pairs
    int is64 = detect_is64(edges);
    int q = blockIdx.x;
    int nw = (n + 1) >> 1;
    for (int i = threadIdx.x; i < nw; i += blockDim.x) hist[i] = 0;
    __syncthreads();
    long long base = (long long)q << CHUNK_LOG;
    long long rem = E - base;
    int m = (rem < (long long)CHUNK) ? (int)rem : CHUNK;
    // 4-wide vector path: full chunk + aligned dst-array start.
    bool vec_ok = (m == CHUNK) && (is64 ? ((E & 1) == 0) : ((E & 3) == 0));
    if (vec_ok) {
      for (int gidx = threadIdx.x; gidx < (CHUNK >> 2); gidx += blockDim.x) {
        long long e0 = base + ((long long)gidx << 2);
        int d0, d1, d2, d3;
        if (is64) {
          const longlong2* p2 = (const longlong2*)edges;
          longlong2 a = p2[(E + e0) >> 1];
          longlong2 b = p2[((E + e0) >> 1) + 1];
          d0 = (int)a.x; d1 = (int)a.y; d2 = (int)b.x; d3 = (int)b.y;
        } else {
          int4 a = ((const int4*)edges)[(E + e0) >> 2];
          d0 = a.x; d1 = a.y; d2 = a.z; d3 = a.w;
        }
        ushort4 rk;
        {
          int sh = (d0 & 1) << 4;
          unsigned int old = atomicAdd(&hist[d0 >> 1], 1u << sh);
          rk.x = (unsigned short)((old >> sh) & 0xffffu);
        }
        {
          int sh = (d1 & 1) << 4;
          unsigned int old = atomicAdd(&hist[d1 >> 1], 1u << sh);
          rk.y = (unsigned short)((old >> sh) & 0xffffu);
        }
        {
          int sh = (d2 & 1) << 4;
          unsigned int old = atomicAdd(&hist[d2 >> 1], 1u << sh);
          rk.z = (unsigned short)((old >> sh) & 0xffffu);
        }
        {
          int sh = (d3 & 1) << 4;
          unsigned int old = atomicAdd(&hist[d3 >> 1], 1u << sh);
          rk.w = (unsigned short)((old >> sh) & 0xffffu);
        }
        *(ushort4*)(rank + e0) = rk;
      }
    } else {
      for (int t = threadIdx.x; t < m; t += blockDim.x) {
        long long e = base + t;
        int dst = load_idx(edges, E + e, is64);
        int sh = (dst & 1) << 4;
        unsigned int old = atomicAdd(&hist[dst >> 1], 1u << sh);
        rank[e] = (unsigned short)((old >> sh) & 0xffffu);
      }
    }
    __syncthreads();
    // transposed write-out: counts[node][q]
    for (int i = threadIdx.x; i < nw; i += blockDim.x) {
      unsigned int v = hist[i];
      int node0 = i << 1;
      counts[(long long)node0 * ncp + q] = (unsigned short)(v & 0xffffu);
      if (node0 + 1 < n)
        counts[(long long)(node0 + 1) * ncp + q] = (unsigned short)(v >> 16);
    }
  } else {
    int tid = ((int)blockIdx.x - nchunk) * (int)blockDim.x + (int)threadIdx.x;
    int n4 = (n + 3) >> 2;
    if (tid >= n4 * 32) return;
    int i4 = tid >> 5;
    int j = (tid & 31) << 2;
    int r0 = i4 << 2;
    if (r0 + 4 <= n) {
      const float4* xr4 = (const float4*)(x + (long long)r0 * FEAT);
      float4 a0 = {0.f,0.f,0.f,0.f}, a1 = a0, a2 = a0, a3 = a0;
      #pragma unroll 2
      for (int k4 = 0; k4 < FEAT / 4; ++k4) {
        float4 xv0 = xr4[k4];
        float4 xv1 = xr4[32 + k4];
        float4 xv2 = xr4[64 + k4];
        float4 xv3 = xr4[96 + k4];
        const float* wb = W1 + (k4 << 2) * FEAT + j;
        float4 w0 = *(const float4*)(wb);
        float4 w1 = *(const float4*)(wb + FEAT);
        float4 w2 = *(const float4*)(wb + 2 * FEAT);
        float4 w3 = *(const float4*)(wb + 3 * FEAT);
        // k = 4*k4 + t, t ascending -> same fma order as scalar version
        a0.x = fmaf(xv0.x, w0.x, a0.x); a0.y = fmaf(xv0.x, w0.y, a0.y);
        a0.z = fmaf(xv0.x, w0.z, a0.z); a0.w = fmaf(xv0.x, w0.w, a0.w);
        a1.x = fmaf(xv1.x, w0.x, a1.x); a1.y = fmaf(xv1.x, w0.y, a1.y);
        a1.z = fmaf(xv1.x, w0.z, a1.z); a1.w = fmaf(xv1.x, w0.w, a1.w);
        a2.x = fmaf(xv2.x, w0.x, a2.x); a2.y = fmaf(xv2.x, w0.y, a2.y);
        a2.z = fmaf(xv2.x, w0.z, a2.z); a2.w = fmaf(xv2.x, w0.w, a2.w);
        a3.x = fmaf(xv3.x, w0.x, a3.x); a3.y = fmaf(xv3.x, w0.y, a3.y);
        a3.z = fmaf(xv3.x, w0.z, a3.z); a3.w = fmaf(xv3.x, w0.w, a3.w);

        a0.x = fmaf(xv0.y, w1.x, a0.x); a0.y = fmaf(xv0.y, w1.y, a0.y);
        a0.z = fmaf(xv0.y, w1.z, a0.z); a0.w = fmaf(xv0.y, w1.w, a0.w);
        a1.x = fmaf(xv1.y, w1.x, a1.x); a1.y = fmaf(xv1.y, w1.y, a1.y);
        a1.z = fmaf(xv1.y, w1.z, a1.z); a1.w = fmaf(xv1.y, w1.w, a1.w);
        a2.x = fmaf(xv2.y, w1.x, a2.x); a2.y = fmaf(xv2.y, w1.y, a2.y);
        a2.z = fmaf(xv2.y, w1.z, a2.z); a2.w = fmaf(xv2.y, w1.w, a2.w);
        a3.x = fmaf(xv3.y, w1.x, a3.x); a3.y = fmaf(xv3.y, w1.y, a3.y);
        a3.z = fmaf(xv3.y, w1.z, a3.z); a3.w = fmaf(xv3.y, w1.w, a3.w);

        a0.x = fmaf(xv0.z, w2.x, a0.x); a0.y = fmaf(xv0.z, w2.y, a0.y);
        a0.z = fmaf(xv0.z, w2.z, a0.z); a0.w = fmaf(xv0.z, w2.w, a0.w);
        a1.x = fmaf(xv1.z, w2.x, a1.x); a1.y = fmaf(xv1.z, w2.y, a1.y);
        a1.z = fmaf(xv1.z, w2.z, a1.z); a1.w = fmaf(xv1.z, w2.w, a1.w);
        a2.x = fmaf(xv2.z, w2.x, a2.x); a2.y = fmaf(xv2.z, w2.y, a2.y);
        a2.z = fmaf(xv2.z, w2.z, a2.z); a2.w = fmaf(xv2.z, w2.w, a2.w);
        a3.x = fmaf(xv3.z, w2.x, a3.x); a3.y = fmaf(xv3.z, w2.y, a3.y);
        a3.z = fmaf(xv3.z, w2.z, a3.z); a3.w = fmaf(xv3.z, w2.w, a3.w);

        a0.x = fmaf(xv0.w, w3.x, a0.x); a0.y = fmaf(xv0.w, w3.y, a0.y);
        a0.z = fmaf(xv0.w, w3.z, a0.z); a0.w = fmaf(xv0.w, w3.w, a0.w);
        a1.x = fmaf(xv1.w, w3.x, a1.x); a1.y = fmaf(xv1.w, w3.y, a1.y);
        a1.z = fmaf(xv1.w, w3.z, a1.z); a1.w = fmaf(xv1.w, w3.w, a1.w);
        a2.x = fmaf(xv2.w, w3.x, a2.x); a2.y = fmaf(xv2.w, w3.y, a2.y);
        a2.z = fmaf(xv2.w, w3.z, a2.z); a2.w = fmaf(xv2.w, w3.w, a2.w);
        a3.x = fmaf(xv3.w, w3.x, a3.x); a3.y = fmaf(xv3.w, w3.y, a3.y);
        a3.z = fmaf(xv3.w, w3.z, a3.z); a3.w = fmaf(xv3.w, w3.w, a3.w);
      }
      *(float4*)(hm1 + (long long)(r0 + 0) * FEAT + j) = a0;
      *(float4*)(hm1 + (long long)(r0 + 1) * FEAT + j) = a1;
      *(float4*)(hm1 + (long long)(r0 + 2) * FEAT + j) = a2;
      *(float4*)(hm1 + (long long)(r0 + 3) * FEAT + j) = a3;
    } else {
      const float* xr = x + (long long)r0 * FEAT;
      for (int r = 0; r0 + r < n; ++r) {
        float4 a = {0.f,0.f,0.f,0.f};
        for (int k = 0; k < FEAT; ++k) {
          float4 w = *(const float4*)(W1 + k * FEAT + j);
          float xv = xr[(long long)r * FEAT + k];
          a.x = fmaf(xv, w.x, a.x); a.y = fmaf(xv, w.y, a.y);
          a.z = fmaf(xv, w.z, a.z); a.w = fmaf(xv, w.w, a.w);
        }
        *(float4*)(hm1 + (long long)(r0 + r) * FEAT + j) = a;
      }
    }
  }
}

// WAVE-per-node: chunk prefix -> counts prefixes + deg + dinv, then the SAME
// wave scales its row (g1h = half(hm1*dinv), 64 lanes x float2->half2).
// Wave i==n zeros the pad row.
__global__ void prefix_scale_kernel(unsigned short* counts, int ncp, int* deg,
                                    float* dinv,
                                    const float* __restrict__ hm1,
                                    __half* __restrict__ g1h, int n, int nchunk) {
  int i = (int)((blockIdx.x * (long long)blockDim.x + threadIdx.x) >> 6);
  int lane = threadIdx.x & 63;
  if (i > n) return;
  if (i == n) {  // zero pad row n (64 lanes x 4B = 256B)
    ((unsigned int*)(g1h + ((long long)n << 7)))[lane] = 0u;
    return;
  }
  int nw32 = (nchunk + 1) >> 1;
  int tot;
  if (nw32 <= 64) {
    unsigned int* r32 = (unsigned int*)(counts + (long long)i * ncp);
    unsigned int v = (lane < nw32) ? r32[lane] : 0u;
    int q0 = lane << 1;
    int c0 = (q0 < nchunk) ? (int)(v & 0xffffu) : 0;
    int c1 = (q0 + 1 < nchunk) ? (int)(v >> 16) : 0;
    int s = c0 + c1;
    int run = s;
    #pragma unroll
    for (int off = 1; off < 64; off <<= 1) {
      int t = __shfl_up(run, off);
      if (lane >= off) run += t;
    }
    int excl = run - s;
    if (lane < nw32)
      r32[lane] = (unsigned int)(excl & 0xffff) |
                  ((unsigned int)((excl + c0) & 0xffff) << 16);
    tot = __shfl(run, 63);
  } else {
    int run = 0;
    if (lane == 0) {
      for (int q = 0; q < nchunk; ++q) {
        long long idx = (long long)i * ncp + q;
        int c = counts[idx];
        counts[idx] = (unsigned short)run;
        run += c;
      }
    }
    tot = __shfl(run, 0);
  }
  float di = rsqrtf((float)tot + 1.0f);  // +1 = self loop
  if (lane == 0) { deg[i] = tot; dinv[i] = di; }
  // scale row i: hm1 (fp32) -> g1h (fp16), element-wise *di
  float2 v = ((const float2*)(hm1 + ((long long)i << 7)))[lane];
  __half2 hv = __floats2half2_rn(v.x * di, v.y * di);
  ((__half2*)g1h)[((long long)i << 6) + lane] = hv;
}

// Padded-CSR fill: pos = (d<<8) + counts[d][r] + rank[e] (u16, no atomics).
__global__ void fill_kernel(const void* edges, long long E,
                            const unsigned short* __restrict__ counts, int ncp,
                            const unsigned short* __restrict__ rank,
                            unsigned short* __restrict__ csr) {
  int is64 = detect_is64(edges);  // all lanes active here
  long long e = blockIdx.x * (long long)blockDim.x + threadIdx.x;
  if (e >= E) return;
  int r = (int)(e >> CHUNK_LOG);
  int s = load_idx(edges, e, is64);
  int d = load_idx(edges, E + e, is64);
  int pos = (d << RSTRIDE_LOG) + (int)counts[(long long)d * ncp + r] + (int)rank[e];
  csr[pos] = (unsigned short)s;
}

// Fused agg1 + gemm2.  4 waves = 4 nodes per block.  W2 staged in LDS.
// Phase 0: cooperative W2 -> LDS (20KB, coalesced float4).
// Phase 1 (per wave): full-row gather, 64 lanes x __half2, fp32 accumulate;
//   h = relu(di*(sum+self) + b1) -> LDS.
// Phase 2 (after one barrier): lanes 0..C-1 compute G2[node][c] =
//   di * sum_k h[k]*W2s[k*C+c]  (k ascending -> bit-identical to L2 version).
__global__ void agg1g2_kernel(const __half* __restrict__ g,
                              const float* __restrict__ dinv,
                              const int* __restrict__ deg,
                              const unsigned short* __restrict__ csr,
                              const float* __restrict__ b1,
                              const float* __restrict__ W2,
                              float* __restrict__ G2, int n, int C) {
  __shared__ float hs[4][FEAT];        // 2 KB
  __shared__ float W2s[FEAT * G2S];    // <= 24 KB (FEAT*C used)
  int lane = threadIdx.x & 63;
  int wid = threadIdx.x >> 6;
  int node = ((int)blockIdx.x << 2) | wid;
  // Phase 0: stage W2 (FEAT*C floats) into LDS, float4 when C%4==0.
  int totw = FEAT * C;
  if ((C & 3) == 0) {
    int tot4 = totw >> 2;
    float4* dst4 = (float4*)W2s;
    const float4* src4 = (const float4*)W2;
    for (int t = threadIdx.x; t < tot4; t += blockDim.x) dst4[t] = src4[t];
  } else {
    for (int t = threadIdx.x; t < totw; t += blockDim.x) W2s[t] = W2[t];
  }
  if (node < n) {
    const unsigned int* gu = (const unsigned int*)g;  // 64 u32 per row
    int beg = node << RSTRIDE_LOG;
    int end = beg + deg[node];
    float ax = 0.f, ay = 0.f;
    for (int base = beg; base < end; base += 64) {
      int ed = (base + lane < end) ? (int)csr[base + lane] : n;  // n -> zero row
      int m = end - base; if (m > 64) m = 64;
      int mm = (m + 15) & ~15;
      for (int j = 0; j < mm; j += 16) {
        int ss[16];
        unsigned int vv[16];
        #pragma unroll
        for (int p = 0; p < 16; ++p) ss[p] = __shfl(ed, j + p);
        #pragma unroll
        for (int p = 0; p < 16; ++p) vv[p] = gu[(ss[p] << 6) + lane];
        #pragma unroll
        for (int p = 0; p < 16; ++p) {
          float2 v = __half22float2(*(__half2*)&vv[p]);
          ax += v.x; ay += v.y;
        }
      }
    }
    float di = dinv[node];
    float2 self = __half22float2(((const __half2*)g)[(node << 6) + lane]);
    ax += self.x; ay += self.y;
    int f = lane << 1;
    ax = fmaxf(ax * di + b1[f], 0.f);
    ay = fmaxf(ay * di + b1[f + 1], 0.f);
    float2* hp = (float2*)&hs[wid][f];
    *hp = make_float2(ax, ay);
  }
  __syncthreads();
  if (node < n) {
    if (lane < C) {
      const float* hr = hs[wid];
      float acc = 0.f;
      #pragma unroll 8
      for (int k = 0; k < FEAT; ++k)
        acc = fmaf(hr[k], W2s[k * C + lane], acc);
      G2[node * G2S + lane] = acc * dinv[node];
    }
  } else if (node == n && lane < C) {
    G2[n * G2S + lane] = 0.f;  // pad row read by agg2
  }
}

// WAVE-per-node. out = di*(sum G2[src] + G2[node]) + b2. Lanes 0..C-1 active.
__global__ void agg2_kernel(const float* __restrict__ G2, const float* __restrict__ dinv,
                            const int* __restrict__ deg,
                            const unsigned short* __restrict__ csr,
                            const float* __restrict__ b2, float* __restrict__ out,
                            int n, int C) {
  int node = (int)((blockIdx.x * (long long)blockDim.x + threadIdx.x) >> 6);
  int lane = threadIdx.x & 63;
  if (node >= n) return;
  int beg = node << RSTRIDE_LOG;
  int end = beg + deg[node];
  float acc = 0.f;
  for (int base = beg; base < end; base += 64) {
    int ed = (base + lane < end) ? (int)csr[base + lane] : n;  // n -> zero row
    int m = end - base; if (m > 64) m = 64;
    int mm = (m + 15) & ~15;
    for (int j = 0; j < mm; j += 16) {
      int ss[16];
      float vv[16];
      #pragma unroll
      for (int p = 0; p < 16; ++p) ss[p] = __shfl(ed, j + p);
      #pragma unroll
      for (int p = 0; p < 16; ++p)
        vv[p] = (lane < C) ? G2[(long long)ss[p] * G2S + lane] : 0.f;
      #pragma unroll
      for (int p = 0; p < 16; ++p) acc += vv[p];
    }
  }
  if (lane < C) {
    float di = dinv[node];
    acc += G2[(long long)node * G2S + lane];
    out[(long long)node * C + lane] = acc * di + b2[lane];
  }
}

extern "C" void kernel_launch(void* const* d_in, const int* in_sizes, int n_in,
                              void* d_out, int out_size, void* d_ws, size_t ws_size,
                              hipStream_t stream) {
  const float* x     = (const float*)d_in[0];
  const void*  edges = d_in[1];
  const float* W1    = (const float*)d_in[2];
  const float* b1    = (const float*)d_in[3];
  const float* W2    = (const float*)d_in[4];
  const float* b2    = (const float*)d_in[5];
  float* out = (float*)d_out;

  const int n = in_sizes[0] / FEAT;
  const long long E = in_sizes[1] / 2;
  const int C = in_sizes[5];
  const int nchunk = (int)((E + CHUNK - 1) >> CHUNK_LOG);
  const int ncp = (nchunk + 1) & ~1;   // even stride (u32-packable rows)

  char* ws = (char*)d_ws;
  size_t off = 0;
  auto alloc = [&](size_t bytes) -> void* {
    void* p = ws + off;
    off = (off + bytes + 255) & ~(size_t)255;
    return p;
  };
  unsigned short* counts = (unsigned short*)alloc(2ll * ncp * n);  // [node][chunk]
  unsigned short* rank   = (unsigned short*)alloc(2ll * E);
  unsigned short* csr    = (unsigned short*)alloc(2ll * n << RSTRIDE_LOG);  // padded
  int*   deg     = (int*)alloc(4ll * n);
  float* dinv    = (float*)alloc(4ll * n);
  float* hm1     = (float*)alloc(4ll * n * FEAT);        // fp32 x @ W1
  __half* g1h    = (__half*)alloc(2ll * (n + 1) * FEAT); // half(hm1*dinv); row n zero
  float* G2      = (float*)alloc(4ll * (n + 1) * G2S);   // row n zero

  int n4 = (n + 3) >> 2;
  const int ABLK = 512;                            // A block size (R11 verified)
  int gemmBlocks = (n4 * 32 + ABLK - 1) / ABLK;
  int blocksE = (int)((E + 255) / 256);
  size_t ldsBytes = (size_t)((n + 1) >> 1) * 4;  // 20 KB at n=10000

  count_gemm1_kernel<<<nchunk + gemmBlocks, ABLK, ldsBytes, stream>>>(
      edges, E, nchunk, counts, ncp, rank, x, W1, hm1, n);
  prefix_scale_kernel<<<(int)(((long long)(n + 1) * 64 + 255) / 256), 256, 0,
                        stream>>>(counts, ncp, deg, dinv, hm1, g1h, n, nchunk);
  fill_kernel<<<blocksE, 256, 0, stream>>>(edges, E, counts, ncp, rank, csr);
  int aggBlocks = (n + 4) >> 2;   // covers nodes 0..n (pad row in last block)
  agg1g2_kernel<<<aggBlocks, 256, 0, stream>>>(g1h, dinv, deg, csr, b1, W2,
                                               G2, n, C);
  agg2_kernel<<<(n4 * 256 + 255) / 256, 256, 0, stream>>>(G2, dinv, deg, csr,
                                                          b2, out, n, C);
}